// Round 8
// baseline (392.004 us; speedup 1.0000x reference)
//
#include <hip/hip_runtime.h>

// GCN 2-layer. R20: zero-global-atomic scan-and-bin scatter + deeper-MLP
// gathers. R19 counters: scatter latency-bound regardless of traffic mix
// (VALUBusy 3.3%, HBM 12%, dur 57us) -> the atomic->rank->random-2B-store
// chain is the cost. Replace it: 160 blocks each OWN a 125-node dst range,
// scan the whole edge list as u16 (dst16, 1.28MB, precompacted in k_pre,
// L1-streamed ~8us/block in parallel), bin matches into a 20KB LDS bucket
// (LDS atomics), write cnt+buckets out coalesced once. No global atomics.
// Gathers: halves-INNER (one idx/cnt load feeds GA+GB gathers; R19's
// halves-outer doubled dependent chains) + 4-deep unroll (32 edges in
// flight, 4 independent chains/lane; mean deg 32 -> one latency round).
// Deferred-dinv algebra retained; h1 LDS-only; g2 pre-scaled by dinv_row.
// Pipeline: k_pre(WT+dst16) -> k_front(scan-bin || gemm1raw) -> k_mid -> k_back.

#define N_NODES 20000
#define N_EDGES 640000
#define IN_DIM 128
#define HID_DIM 128
#define OUT_DIM 64

#define STRIDE 80
#define SC_NB 160
#define NODES_PB (N_NODES / SC_NB)           // 125 nodes per scatter block
#define G1_NB 625                            // 2500 wave-tasks / 4
#define G1_TASKS (2 * (N_NODES / 16))        // 2500
#define PRE_NB 176

typedef _Float16 half8_t __attribute__((ext_vector_type(8)));
typedef float float4_t __attribute__((ext_vector_type(4)));
typedef unsigned short ushort8_t __attribute__((ext_vector_type(8)));

// k_pre: WT1/WT2 transpose+cast + dst compaction int32 -> u16 (node ids
// < 20000 fit u16; 2.56MB -> 1.28MB halves every scan-block's L1 stream).
__global__ __launch_bounds__(256) void k_pre(const float* __restrict__ W1,
                                             const float* __restrict__ W2,
                                             _Float16* __restrict__ WT1,
                                             _Float16* __restrict__ WT2,
                                             const int* __restrict__ dst,
                                             unsigned short* __restrict__ dst16) {
    const int i = blockIdx.x * 256 + threadIdx.x;
    if (i < 128 * 128) {
        int c = i >> 7, k = i & 127;
        WT1[i] = (_Float16)W1[k * 128 + c];
    } else if (i < 128 * 128 + 64 * 128) {
        int o = i - 128 * 128;
        int c = o >> 7, k = o & 127;
        WT2[o] = (_Float16)W2[k * 64 + c];
    }
    for (int e = i; e < N_EDGES; e += PRE_NB * 256)
        dst16[e] = (unsigned short)dst[e];
}

// k_front: blocks [0,SC_NB): scan-and-bin. Block owns dst range
// [b*125,(b+1)*125); scans all 640K dst16 (ushort8 loads, L1-streamed),
// matches -> LDS bucket via LDS atomicAdd rank; then ONE coalesced writeout
// of cnt (exact counts) + bucket rows. Blocks [SC_NB,...): gemm1 RAW
// GA/GB = x@W1 halves (deferred dinv -> independent of the scatter).
__global__ __launch_bounds__(256) void k_front(const int* __restrict__ src,
                                               const unsigned short* __restrict__ dst16,
                                               int* __restrict__ cnt,
                                               unsigned short* __restrict__ esrc_pad,
                                               const _Float16* __restrict__ WT1,
                                               const float* __restrict__ x,
                                               _Float16* __restrict__ GA,
                                               _Float16* __restrict__ GB) {
    __shared__ unsigned short lbuck[NODES_PB * STRIDE];   // 20000 B
    __shared__ int lhist[NODES_PB];
    const int b = blockIdx.x, tid = threadIdx.x;
    if (b < SC_NB) {
        for (int i = tid; i < NODES_PB; i += 256) lhist[i] = 0;
        __syncthreads();
        const unsigned int lo = b * NODES_PB;
        const ushort8_t* d8 = (const ushort8_t*)dst16;
        for (int i = tid; i < N_EDGES / 8; i += 256) {
            ushort8_t dv = d8[i];   // cached: reused by all blocks on the XCD
            const int e0 = i * 8;
#pragma unroll
            for (int q = 0; q < 8; ++q) {
                unsigned int ln = (unsigned int)dv[q] - lo;
                if (ln < (unsigned int)NODES_PB) {
                    int s = src[e0 + q];
                    int r = atomicAdd(&lhist[ln], 1);
                    if (r < STRIDE) lbuck[ln * STRIDE + r] = (unsigned short)s;
                }
            }
        }
        __syncthreads();
        for (int i = tid; i < NODES_PB; i += 256) cnt[lo + i] = lhist[i];
        const unsigned int* ls = (const unsigned int*)lbuck;
        unsigned int* gd = (unsigned int*)(esrc_pad + (size_t)lo * STRIDE);
        for (int i = tid; i < NODES_PB * STRIDE / 2; i += 256) gd[i] = ls[i];
        return;
    }
    // ---- gemm1 raw, GA/GB halves ----
    const int wave = tid >> 6;
    const int lane = tid & 63;
    const int task = (b - SC_NB) * 4 + wave;
    if (task >= G1_TASKS) return;
    const int strip = task >> 1;
    const int nh = task & 1;
    const int row0 = strip * 16;
    const int mrow = row0 + (lane & 15);
    const int kq = (lane >> 4) * 8;
    _Float16* G = nh ? GB : GA;

    half8_t af[4];
#pragma unroll
    for (int kc = 0; kc < 4; ++kc) {
        const float* ap = x + (size_t)mrow * 128 + kc * 32 + kq;
        float4_t f0 = __builtin_nontemporal_load((const float4_t*)ap);
        float4_t f1 = __builtin_nontemporal_load((const float4_t*)(ap + 4));
        half8_t h;
        h[0] = (_Float16)f0[0]; h[1] = (_Float16)f0[1];
        h[2] = (_Float16)f0[2]; h[3] = (_Float16)f0[3];
        h[4] = (_Float16)f1[0]; h[5] = (_Float16)f1[1];
        h[6] = (_Float16)f1[2]; h[7] = (_Float16)f1[3];
        af[kc] = h;
    }
    float4_t acc[4];
#pragma unroll
    for (int nt = 0; nt < 4; ++nt) acc[nt] = (float4_t)(0.0f);
#pragma unroll
    for (int nt = 0; nt < 4; ++nt) {
        const _Float16* wp = WT1 + (size_t)((nh * 4 + nt) * 16 + (lane & 15)) * 128 + kq;
#pragma unroll
        for (int kc = 0; kc < 4; ++kc) {
            half8_t bf = *(const half8_t*)(wp + kc * 32);
            acc[nt] = __builtin_amdgcn_mfma_f32_16x16x32_f16(af[kc], bf, acc[nt], 0, 0, 0);
        }
    }
#pragma unroll
    for (int r = 0; r < 4; ++r) {
        int row = row0 + (lane >> 4) * 4 + r;
#pragma unroll
        for (int nt = 0; nt < 4; ++nt)
            G[(size_t)row * 64 + nt * 16 + (lane & 15)] = (_Float16)acc[nt][r];
    }
}

// K_mid: one block per 16-node strip. Phase A: halves-INNER (one idx/cnt
// load feeds GA+GB gathers), 4-deep unroll = 32 edges in flight per wave;
// 8 edge-slots x 8 lanes (fl covers 64 cols = 128B row). h1 (relu+bias+dvd)
// -> LDS only. Phase B: MFMA h1 @ WT2, epilogue pre-scales by dinv_row.
__global__ __launch_bounds__(256) void k_mid(const int* __restrict__ cnt,
                                             const unsigned short* __restrict__ esrc_pad,
                                             const _Float16* __restrict__ GA,
                                             const _Float16* __restrict__ GB,
                                             const _Float16* __restrict__ WT2,
                                             const float* __restrict__ b1,
                                             _Float16* __restrict__ g2) {
    __shared__ _Float16 h1[16][136];
    const int tid = threadIdx.x;
    const int wave = tid >> 6;
    const int lane = tid & 63;
    const int row0 = blockIdx.x * 16;
    const int eidx = lane >> 3;   // 8 edge slots
    const int fl = lane & 7;      // 8 col-groups of 8 (64 cols per table)

    for (int r4 = 0; r4 < 4; ++r4) {
        const int rr = wave * 4 + r4;
        const int node = row0 + rr;
        const int endt = cnt[node];
        const float dvd = rsqrtf((float)endt + 1.0f);
        const int end = endt < STRIDE ? endt : STRIDE;
        const int base = node * STRIDE;

        float accA[8], accB[8];
#pragma unroll
        for (int p = 0; p < 8; ++p) { accA[p] = 0.0f; accB[p] = 0.0f; }
        if (lane < 8) {  // self-loop term dvd * G[node]
            half8_t sa = *(const half8_t*)(GA + (size_t)node * 64 + fl * 8);
            half8_t sb = *(const half8_t*)(GB + (size_t)node * 64 + fl * 8);
#pragma unroll
            for (int p = 0; p < 8; ++p) {
                accA[p] = dvd * (float)sa[p];
                accB[p] = dvd * (float)sb[p];
            }
        }
        int j = 0;
        for (; j + 31 < end; j += 32) {
            int s0 = (int)esrc_pad[base + j + eidx];
            int s1 = (int)esrc_pad[base + j + 8 + eidx];
            int s2 = (int)esrc_pad[base + j + 16 + eidx];
            int s3 = (int)esrc_pad[base + j + 24 + eidx];
            float d0 = rsqrtf((float)cnt[s0] + 1.0f);
            float d1 = rsqrtf((float)cnt[s1] + 1.0f);
            float d2 = rsqrtf((float)cnt[s2] + 1.0f);
            float d3 = rsqrtf((float)cnt[s3] + 1.0f);
            half8_t a0 = *(const half8_t*)(GA + (size_t)s0 * 64 + fl * 8);
            half8_t a1 = *(const half8_t*)(GA + (size_t)s1 * 64 + fl * 8);
            half8_t a2 = *(const half8_t*)(GA + (size_t)s2 * 64 + fl * 8);
            half8_t a3 = *(const half8_t*)(GA + (size_t)s3 * 64 + fl * 8);
            half8_t v0 = *(const half8_t*)(GB + (size_t)s0 * 64 + fl * 8);
            half8_t v1 = *(const half8_t*)(GB + (size_t)s1 * 64 + fl * 8);
            half8_t v2 = *(const half8_t*)(GB + (size_t)s2 * 64 + fl * 8);
            half8_t v3 = *(const half8_t*)(GB + (size_t)s3 * 64 + fl * 8);
#pragma unroll
            for (int p = 0; p < 8; ++p) {
                accA[p] += d0 * (float)a0[p] + d1 * (float)a1[p] +
                           d2 * (float)a2[p] + d3 * (float)a3[p];
                accB[p] += d0 * (float)v0[p] + d1 * (float)v1[p] +
                           d2 * (float)v2[p] + d3 * (float)v3[p];
            }
        }
        for (; j + 15 < end; j += 16) {
            int s0 = (int)esrc_pad[base + j + eidx];
            int s1 = (int)esrc_pad[base + j + 8 + eidx];
            float d0 = rsqrtf((float)cnt[s0] + 1.0f);
            float d1 = rsqrtf((float)cnt[s1] + 1.0f);
            half8_t a0 = *(const half8_t*)(GA + (size_t)s0 * 64 + fl * 8);
            half8_t a1 = *(const half8_t*)(GA + (size_t)s1 * 64 + fl * 8);
            half8_t v0 = *(const half8_t*)(GB + (size_t)s0 * 64 + fl * 8);
            half8_t v1 = *(const half8_t*)(GB + (size_t)s1 * 64 + fl * 8);
#pragma unroll
            for (int p = 0; p < 8; ++p) {
                accA[p] += d0 * (float)a0[p] + d1 * (float)a1[p];
                accB[p] += d0 * (float)v0[p] + d1 * (float)v1[p];
            }
        }
        for (; j + 7 < end; j += 8) {
            int s = (int)esrc_pad[base + j + eidx];
            float dv = rsqrtf((float)cnt[s] + 1.0f);
            half8_t a = *(const half8_t*)(GA + (size_t)s * 64 + fl * 8);
            half8_t v = *(const half8_t*)(GB + (size_t)s * 64 + fl * 8);
#pragma unroll
            for (int p = 0; p < 8; ++p) {
                accA[p] += dv * (float)a[p];
                accB[p] += dv * (float)v[p];
            }
        }
        if (j < end) {
            int idx = j + eidx;
            int s = (int)esrc_pad[base + ((idx < end) ? idx : (end - 1))];
            float valid = (idx < end) ? 1.0f : 0.0f;
            float dv = valid * rsqrtf((float)cnt[s] + 1.0f);
            half8_t a = *(const half8_t*)(GA + (size_t)s * 64 + fl * 8);
            half8_t v = *(const half8_t*)(GB + (size_t)s * 64 + fl * 8);
#pragma unroll
            for (int p = 0; p < 8; ++p) {
                accA[p] += dv * (float)a[p];
                accB[p] += dv * (float)v[p];
            }
        }
#pragma unroll
        for (int p = 0; p < 8; ++p) {
            accA[p] += __shfl_xor(accA[p], 8, 64);
            accA[p] += __shfl_xor(accA[p], 16, 64);
            accA[p] += __shfl_xor(accA[p], 32, 64);
            accB[p] += __shfl_xor(accB[p], 8, 64);
            accB[p] += __shfl_xor(accB[p], 16, 64);
            accB[p] += __shfl_xor(accB[p], 32, 64);
        }
        if (lane < 8) {
            float4_t c0 = *(const float4_t*)(b1 + fl * 8);
            float4_t c1 = *(const float4_t*)(b1 + fl * 8 + 4);
            float4_t c2 = *(const float4_t*)(b1 + 64 + fl * 8);
            float4_t c3 = *(const float4_t*)(b1 + 64 + fl * 8 + 4);
            half8_t oa, ob;
            oa[0] = (_Float16)fmaxf(accA[0] * dvd + c0[0], 0.0f);
            oa[1] = (_Float16)fmaxf(accA[1] * dvd + c0[1], 0.0f);
            oa[2] = (_Float16)fmaxf(accA[2] * dvd + c0[2], 0.0f);
            oa[3] = (_Float16)fmaxf(accA[3] * dvd + c0[3], 0.0f);
            oa[4] = (_Float16)fmaxf(accA[4] * dvd + c1[0], 0.0f);
            oa[5] = (_Float16)fmaxf(accA[5] * dvd + c1[1], 0.0f);
            oa[6] = (_Float16)fmaxf(accA[6] * dvd + c1[2], 0.0f);
            oa[7] = (_Float16)fmaxf(accA[7] * dvd + c1[3], 0.0f);
            ob[0] = (_Float16)fmaxf(accB[0] * dvd + c2[0], 0.0f);
            ob[1] = (_Float16)fmaxf(accB[1] * dvd + c2[1], 0.0f);
            ob[2] = (_Float16)fmaxf(accB[2] * dvd + c2[2], 0.0f);
            ob[3] = (_Float16)fmaxf(accB[3] * dvd + c2[3], 0.0f);
            ob[4] = (_Float16)fmaxf(accB[4] * dvd + c3[0], 0.0f);
            ob[5] = (_Float16)fmaxf(accB[5] * dvd + c3[1], 0.0f);
            ob[6] = (_Float16)fmaxf(accB[6] * dvd + c3[2], 0.0f);
            ob[7] = (_Float16)fmaxf(accB[7] * dvd + c3[3], 0.0f);
            *(half8_t*)&h1[rr][fl * 8] = oa;
            *(half8_t*)&h1[rr][64 + fl * 8] = ob;
        }
    }
    __syncthreads();

    // ---- Phase B: gemm2 for this strip, PRE-SCALED by dinv_row ----
    const int fr = lane & 15;
    const int kq = (lane >> 4) * 8;
    half8_t af[4];
#pragma unroll
    for (int kc = 0; kc < 4; ++kc)
        af[kc] = *(const half8_t*)&h1[fr][kc * 32 + kq];
    float4_t acc2 = (float4_t)(0.0f);
    const _Float16* wp = WT2 + (size_t)(wave * 16 + fr) * 128 + kq;
#pragma unroll
    for (int kc = 0; kc < 4; ++kc) {
        half8_t bf = *(const half8_t*)(wp + kc * 32);
        acc2 = __builtin_amdgcn_mfma_f32_16x16x32_f16(af[kc], bf, acc2, 0, 0, 0);
    }
#pragma unroll
    for (int r = 0; r < 4; ++r) {
        int row = row0 + (lane >> 4) * 4 + r;
        float dvr = rsqrtf((float)cnt[row] + 1.0f);
        g2[(size_t)row * 64 + wave * 16 + fr] = (_Float16)(dvr * acc2[r]);
    }
}

// K_back: g2 pre-scaled -> out_d = dvd*(sum g2'_s + g2'_d) + b2.
// One wave/node, 4-deep unroll = 32 edges in flight, no cnt lookups.
__global__ __launch_bounds__(256) void k_back(const int* __restrict__ cnt,
                                              const unsigned short* __restrict__ esrc_pad,
                                              const _Float16* __restrict__ g2,
                                              const float* __restrict__ b2,
                                              float* __restrict__ out) {
    const int wave = threadIdx.x >> 6;
    const int lane = threadIdx.x & 63;
    const int node = blockIdx.x * 4 + wave;
    if (node >= N_NODES) return;
    const int eidx = lane >> 3;
    const int fl = lane & 7;

    const int endt = cnt[node];
    const float dvd = rsqrtf((float)endt + 1.0f);
    const int end = endt < STRIDE ? endt : STRIDE;
    const int base = node * STRIDE;

    float acc[8];
#pragma unroll
    for (int p = 0; p < 8; ++p) acc[p] = 0.0f;
    if (lane < 8) {
        half8_t s = *(const half8_t*)(g2 + (size_t)node * 64 + fl * 8);
#pragma unroll
        for (int p = 0; p < 8; ++p) acc[p] = (float)s[p];
    }

    int j = 0;
    for (; j + 31 < end; j += 32) {
        int s0 = (int)esrc_pad[base + j + eidx];
        int s1 = (int)esrc_pad[base + j + 8 + eidx];
        int s2 = (int)esrc_pad[base + j + 16 + eidx];
        int s3 = (int)esrc_pad[base + j + 24 + eidx];
        half8_t r0 = *(const half8_t*)(g2 + (size_t)s0 * 64 + fl * 8);
        half8_t r1 = *(const half8_t*)(g2 + (size_t)s1 * 64 + fl * 8);
        half8_t r2 = *(const half8_t*)(g2 + (size_t)s2 * 64 + fl * 8);
        half8_t r3 = *(const half8_t*)(g2 + (size_t)s3 * 64 + fl * 8);
#pragma unroll
        for (int p = 0; p < 8; ++p)
            acc[p] += ((float)r0[p] + (float)r1[p]) + ((float)r2[p] + (float)r3[p]);
    }
    for (; j + 15 < end; j += 16) {
        int s0 = (int)esrc_pad[base + j + eidx];
        int s1 = (int)esrc_pad[base + j + 8 + eidx];
        half8_t r0 = *(const half8_t*)(g2 + (size_t)s0 * 64 + fl * 8);
        half8_t r1 = *(const half8_t*)(g2 + (size_t)s1 * 64 + fl * 8);
#pragma unroll
        for (int p = 0; p < 8; ++p) acc[p] += (float)r0[p] + (float)r1[p];
    }
    for (; j + 7 < end; j += 8) {
        int s = (int)esrc_pad[base + j + eidx];
        half8_t r = *(const half8_t*)(g2 + (size_t)s * 64 + fl * 8);
#pragma unroll
        for (int p = 0; p < 8; ++p) acc[p] += (float)r[p];
    }
    if (j < end) {
        int idx = j + eidx;
        int s = (int)esrc_pad[base + ((idx < end) ? idx : (end - 1))];
        float valid = (idx < end) ? 1.0f : 0.0f;
        half8_t r = *(const half8_t*)(g2 + (size_t)s * 64 + fl * 8);
#pragma unroll
        for (int p = 0; p < 8; ++p) acc[p] += valid * (float)r[p];
    }

#pragma unroll
    for (int p = 0; p < 8; ++p) {
        acc[p] += __shfl_xor(acc[p], 8, 64);
        acc[p] += __shfl_xor(acc[p], 16, 64);
        acc[p] += __shfl_xor(acc[p], 32, 64);
    }

    if (lane < 8) {
        float4_t c0 = *(const float4_t*)(b2 + fl * 8);
        float4_t c1 = *(const float4_t*)(b2 + fl * 8 + 4);
        float4_t o0, o1;
        o0[0] = acc[0] * dvd + c0[0]; o0[1] = acc[1] * dvd + c0[1];
        o0[2] = acc[2] * dvd + c0[2]; o0[3] = acc[3] * dvd + c0[3];
        o1[0] = acc[4] * dvd + c1[0]; o1[1] = acc[5] * dvd + c1[1];
        o1[2] = acc[6] * dvd + c1[2]; o1[3] = acc[7] * dvd + c1[3];
        __builtin_nontemporal_store(o0, (float4_t*)(out + (size_t)node * 64 + fl * 8));
        __builtin_nontemporal_store(o1, (float4_t*)(out + (size_t)node * 64 + fl * 8 + 4));
    }
}

extern "C" void kernel_launch(void* const* d_in, const int* in_sizes, int n_in,
                              void* d_out, int out_size, void* d_ws, size_t ws_size,
                              hipStream_t stream) {
    const float* x  = (const float*)d_in[0];
    const int*   ei = (const int*)d_in[1];
    const float* W1 = (const float*)d_in[2];
    const float* b1 = (const float*)d_in[3];
    const float* W2 = (const float*)d_in[4];
    const float* b2 = (const float*)d_in[5];

    const int* src = ei;
    const int* dst = ei + N_EDGES;

    char* w = (char*)d_ws;
    unsigned short* esrc_pad = (unsigned short*)w; w += sizeof(unsigned short) * (size_t)N_NODES * STRIDE;
    unsigned short* dst16    = (unsigned short*)w; w += sizeof(unsigned short) * (size_t)N_EDGES;
    _Float16*       GA       = (_Float16*)w;       w += sizeof(_Float16) * (size_t)N_NODES * 64;
    _Float16*       GB       = (_Float16*)w;       w += sizeof(_Float16) * (size_t)N_NODES * 64;
    _Float16*       g2       = (_Float16*)w;       w += sizeof(_Float16) * (size_t)N_NODES * OUT_DIM;
    _Float16*       WT1      = (_Float16*)w;       w += sizeof(_Float16) * 128 * 128;
    _Float16*       WT2      = (_Float16*)w;       w += sizeof(_Float16) * 64 * 128;
    int*            cnt      = (int*)w;            w += sizeof(int) * N_NODES;
    float*          out      = (float*)d_out;

    k_pre<<<PRE_NB, 256, 0, stream>>>(W1, W2, WT1, WT2, dst, dst16);
    k_front<<<SC_NB + G1_NB, 256, 0, stream>>>(src, dst16, cnt, esrc_pad, WT1, x, GA, GB);
    k_mid<<<N_NODES / 16, 256, 0, stream>>>(cnt, esrc_pad, GA, GB, WT2, b1, g2);
    k_back<<<(N_NODES + 3) / 4, 256, 0, stream>>>(cnt, esrc_pad, g2, b2, out);
}

// Round 9
// 164.902 us; speedup vs baseline: 2.3772x; 2.3772x over previous
//
#include <hip/hip_runtime.h>

// GCN 2-layer. R21: revert scatter to the known-good atomic build (R18,
// 53us; R20's scan-and-bin was 160x work amplification at 8% occupancy ->
// 287us). New: aggregation latency fix. Aggs have been ~100us across every
// structural variant while throughput math says ~10us -> they are latency-
// serialized (variable-trip loops don't software-pipeline: idx->wait->
// gather->wait->acc ~700cy x rounds). Fix: deg<=80, 99.9% <=64 -> fixed
// 8-round full unroll with static indices: load all 8 slot-indices (clamped
// to [0,N) so speculative gathers on padding garbage stay in-bounds, masked
// by valid=0), then all cnt loads + all 8 row-gathers issue together under
// vmcnt, then masked accumulate. 2 latency rounds/node instead of 8. Rare
// deg>64: tail loop. k_mid un-fused (h1p round trip is only ~3us of BW;
// the fusion serialized 4 nodes/wave).
// Deferred-dinv algebra retained: G=x@W1 raw; h1=relu(dvd*(sum dvs*G_s +
// dvd*G_d)+b1); g2'=dinv_row*(h1@W2); out=dvd*(sum g2'_s + g2'_d)+b2.
// Pipeline: k_pre -> k_build(scatter||gemm1raw) -> k_agg1 -> k_g2 -> k_agg2.

#define N_NODES 20000
#define N_EDGES 640000
#define IN_DIM 128
#define HID_DIM 128
#define OUT_DIM 64

#define STRIDE 80
#define SCAT_NB (N_EDGES / 256)              // 2500
#define G1_NB 625                            // 2500 wave-tasks / 4
#define G1_TASKS (2 * (N_NODES / 16))        // 2500
#define PRE_ITEMS (128 * 128 + 64 * 128 + N_NODES)
#define PRE_NB ((PRE_ITEMS + 255) / 256)     // 176
#define AGG_NB (N_NODES / 4)                 // 5000

typedef _Float16 half8_t __attribute__((ext_vector_type(8)));
typedef float float4_t __attribute__((ext_vector_type(4)));

// k_pre: WT1/WT2 transpose+cast (fp32 [k][c] -> fp16 [c][k]) + cnt zeroing.
__global__ __launch_bounds__(256) void k_pre(const float* __restrict__ W1,
                                             const float* __restrict__ W2,
                                             _Float16* __restrict__ WT1,
                                             _Float16* __restrict__ WT2,
                                             int* __restrict__ cnt) {
    int i = blockIdx.x * 256 + threadIdx.x;
    if (i < 128 * 128) {
        int c = i >> 7, k = i & 127;
        WT1[i] = (_Float16)W1[k * 128 + c];
    } else if (i < 128 * 128 + 64 * 128) {
        int o = i - 128 * 128;
        int c = o >> 7, k = o & 127;
        WT2[o] = (_Float16)W2[k * 64 + c];
    } else {
        int n = i - (128 * 128 + 64 * 128);
        if (n < N_NODES) cnt[n] = 0;
    }
}

// k_build: blocks [0,SCAT_NB): atomic scatter (1 edge/thread: rank via
// global atomicAdd on cnt, u16 store into padded bucket). Blocks
// [SCAT_NB,...): gemm1 RAW GA/GB = x@W1 column halves (deferred dinv ->
// independent of the scatter; WT1 from k_pre across a kernel boundary).
__global__ __launch_bounds__(256) void k_build(const int* __restrict__ src,
                                               const int* __restrict__ dst,
                                               int* __restrict__ cnt,
                                               unsigned short* __restrict__ esrc_pad,
                                               const _Float16* __restrict__ WT1,
                                               const float* __restrict__ x,
                                               _Float16* __restrict__ GA,
                                               _Float16* __restrict__ GB) {
    const int b = blockIdx.x, tid = threadIdx.x;
    if (b < SCAT_NB) {
        const int e = b * 256 + tid;
        const int s = __builtin_nontemporal_load(&src[e]);
        const int d = __builtin_nontemporal_load(&dst[e]);
        unsigned int rank = atomicAdd((unsigned int*)&cnt[d], 1u);
        if (rank < STRIDE) esrc_pad[d * STRIDE + rank] = (unsigned short)s;
        return;
    }
    // ---- gemm1 raw, GA/GB halves ----
    const int wave = tid >> 6;
    const int lane = tid & 63;
    const int task = (b - SCAT_NB) * 4 + wave;
    if (task >= G1_TASKS) return;
    const int strip = task >> 1;
    const int nh = task & 1;
    const int row0 = strip * 16;
    const int mrow = row0 + (lane & 15);
    const int kq = (lane >> 4) * 8;
    _Float16* G = nh ? GB : GA;

    half8_t af[4];
#pragma unroll
    for (int kc = 0; kc < 4; ++kc) {
        const float* ap = x + (size_t)mrow * 128 + kc * 32 + kq;
        float4_t f0 = __builtin_nontemporal_load((const float4_t*)ap);
        float4_t f1 = __builtin_nontemporal_load((const float4_t*)(ap + 4));
        half8_t h;
        h[0] = (_Float16)f0[0]; h[1] = (_Float16)f0[1];
        h[2] = (_Float16)f0[2]; h[3] = (_Float16)f0[3];
        h[4] = (_Float16)f1[0]; h[5] = (_Float16)f1[1];
        h[6] = (_Float16)f1[2]; h[7] = (_Float16)f1[3];
        af[kc] = h;
    }
    float4_t acc[4];
#pragma unroll
    for (int nt = 0; nt < 4; ++nt) acc[nt] = (float4_t)(0.0f);
#pragma unroll
    for (int nt = 0; nt < 4; ++nt) {
        const _Float16* wp = WT1 + (size_t)((nh * 4 + nt) * 16 + (lane & 15)) * 128 + kq;
#pragma unroll
        for (int kc = 0; kc < 4; ++kc) {
            half8_t bf = *(const half8_t*)(wp + kc * 32);
            acc[nt] = __builtin_amdgcn_mfma_f32_16x16x32_f16(af[kc], bf, acc[nt], 0, 0, 0);
        }
    }
#pragma unroll
    for (int r = 0; r < 4; ++r) {
        int row = row0 + (lane >> 4) * 4 + r;
#pragma unroll
        for (int nt = 0; nt < 4; ++nt)
            G[(size_t)row * 64 + nt * 16 + (lane & 15)] = (_Float16)acc[nt][r];
    }
}

// k_agg1: one wave per (node, col-half). Blocks [0,AGG_NB): half 0 (GA,
// cols 0-63); [AGG_NB,2*AGG_NB): half 1 (GB, cols 64-127). Fixed 8-round
// prefetch: all idx loads issue, then all cnt+row-gathers (independent,
// in flight under vmcnt), then masked accumulate -> 2 latency rounds/node.
// Writes h1p fp16 (relu+bias+dvd applied).
__global__ __launch_bounds__(256) void k_agg1(const int* __restrict__ cnt,
                                              const unsigned short* __restrict__ esrc_pad,
                                              const _Float16* __restrict__ GA,
                                              const _Float16* __restrict__ GB,
                                              const float* __restrict__ b1,
                                              _Float16* __restrict__ h1p) {
    const int half = (blockIdx.x >= AGG_NB) ? 1 : 0;
    const int bb = blockIdx.x - half * AGG_NB;
    const int wave = threadIdx.x >> 6;
    const int lane = threadIdx.x & 63;
    const int node = bb * 4 + wave;
    const _Float16* __restrict__ G = half ? GB : GA;
    const int COL0 = half << 6;
    const int eidx = lane >> 3;
    const int fl = lane & 7;

    const int endt = cnt[node];
    const float dvd = rsqrtf((float)endt + 1.0f);
    const int end = endt < STRIDE ? endt : STRIDE;
    const int base = node * STRIDE;

    // ---- prefetch phase: 8 rounds, static indices ----
    int sv[8];
#pragma unroll
    for (int k = 0; k < 8; ++k) {
        int raw = (int)esrc_pad[base + 8 * k + eidx];
        sv[k] = raw < N_NODES ? raw : (N_NODES - 1);   // clamp: garbage slots masked below
    }
    float dvs[8];
#pragma unroll
    for (int k = 0; k < 8; ++k) {
        float valid = (8 * k + eidx < end) ? 1.0f : 0.0f;
        dvs[k] = valid * rsqrtf((float)cnt[sv[k]] + 1.0f);
    }
    half8_t rv[8];
#pragma unroll
    for (int k = 0; k < 8; ++k)
        rv[k] = *(const half8_t*)(G + (size_t)sv[k] * 64 + fl * 8);

    float acc[8];
#pragma unroll
    for (int p = 0; p < 8; ++p) acc[p] = 0.0f;
    if (lane < 8) {  // self-loop term dvd * G[node]
        half8_t s = *(const half8_t*)(G + (size_t)node * 64 + fl * 8);
#pragma unroll
        for (int p = 0; p < 8; ++p) acc[p] = dvd * (float)s[p];
    }
#pragma unroll
    for (int k = 0; k < 8; ++k)
#pragma unroll
        for (int p = 0; p < 8; ++p) acc[p] += dvs[k] * (float)rv[k][p];

    // ---- rare tail: deg in (64, 80] ----
    for (int j = 64; j < end; j += 8) {
        int idx = j + eidx;
        int s = (int)esrc_pad[base + ((idx < end) ? idx : (end - 1))];
        float valid = (idx < end) ? 1.0f : 0.0f;
        float dv = valid * rsqrtf((float)cnt[s] + 1.0f);
        half8_t r = *(const half8_t*)(G + (size_t)s * 64 + fl * 8);
#pragma unroll
        for (int p = 0; p < 8; ++p) acc[p] += dv * (float)r[p];
    }

#pragma unroll
    for (int p = 0; p < 8; ++p) {
        acc[p] += __shfl_xor(acc[p], 8, 64);
        acc[p] += __shfl_xor(acc[p], 16, 64);
        acc[p] += __shfl_xor(acc[p], 32, 64);
    }

    if (lane < 8) {
        float4_t c0 = *(const float4_t*)(b1 + COL0 + fl * 8);
        float4_t c1 = *(const float4_t*)(b1 + COL0 + fl * 8 + 4);
        half8_t o;
        o[0] = (_Float16)fmaxf(acc[0] * dvd + c0[0], 0.0f);
        o[1] = (_Float16)fmaxf(acc[1] * dvd + c0[1], 0.0f);
        o[2] = (_Float16)fmaxf(acc[2] * dvd + c0[2], 0.0f);
        o[3] = (_Float16)fmaxf(acc[3] * dvd + c0[3], 0.0f);
        o[4] = (_Float16)fmaxf(acc[4] * dvd + c1[0], 0.0f);
        o[5] = (_Float16)fmaxf(acc[5] * dvd + c1[1], 0.0f);
        o[6] = (_Float16)fmaxf(acc[6] * dvd + c1[2], 0.0f);
        o[7] = (_Float16)fmaxf(acc[7] * dvd + c1[3], 0.0f);
        *(half8_t*)(h1p + (size_t)node * 128 + COL0 + fl * 8) = o;
    }
}

// k_g2: g2' = dinv_row * (h1p @ W2). MFMA f16, pre-scaled epilogue so
// k_agg2 needs no per-edge cnt lookups.
__global__ __launch_bounds__(256) void k_g2(const _Float16* __restrict__ A,
                                            const _Float16* __restrict__ WT,
                                            const int* __restrict__ cnt,
                                            _Float16* __restrict__ G) {
    const int wave = threadIdx.x >> 6;
    const int lane = threadIdx.x & 63;
    const int task = blockIdx.x * 4 + wave;
    if (task >= G1_TASKS) return;
    const int strip = task >> 1;
    const int nh = task & 1;
    const int row0 = strip * 16;
    const int mrow = row0 + (lane & 15);
    const int kq = (lane >> 4) * 8;

    half8_t af[4];
#pragma unroll
    for (int kc = 0; kc < 4; ++kc)
        af[kc] = __builtin_nontemporal_load(
            (const half8_t*)(A + (size_t)mrow * 128 + kc * 32 + kq));

    float4_t acc[2];
#pragma unroll
    for (int nt = 0; nt < 2; ++nt) acc[nt] = (float4_t)(0.0f);
#pragma unroll
    for (int nt = 0; nt < 2; ++nt) {
        const _Float16* wp = WT + (size_t)((nh * 2 + nt) * 16 + (lane & 15)) * 128 + kq;
#pragma unroll
        for (int kc = 0; kc < 4; ++kc) {
            half8_t bf = *(const half8_t*)(wp + kc * 32);
            acc[nt] = __builtin_amdgcn_mfma_f32_16x16x32_f16(af[kc], bf, acc[nt], 0, 0, 0);
        }
    }
#pragma unroll
    for (int r = 0; r < 4; ++r) {
        int row = row0 + (lane >> 4) * 4 + r;
        float dvr = rsqrtf((float)cnt[row] + 1.0f);
#pragma unroll
        for (int nt = 0; nt < 2; ++nt)
            G[(size_t)row * 64 + (nh * 2 + nt) * 16 + (lane & 15)] =
                (_Float16)(dvr * acc[nt][r]);
    }
}

// k_agg2: g2' pre-scaled -> out_d = dvd*(sum g2'_s + g2'_d) + b2.
// One wave/node, fixed 8-round prefetch + rare tail.
__global__ __launch_bounds__(256) void k_agg2(const int* __restrict__ cnt,
                                              const unsigned short* __restrict__ esrc_pad,
                                              const _Float16* __restrict__ g2,
                                              const float* __restrict__ b2,
                                              float* __restrict__ out) {
    const int wave = threadIdx.x >> 6;
    const int lane = threadIdx.x & 63;
    const int node = blockIdx.x * 4 + wave;
    const int eidx = lane >> 3;
    const int fl = lane & 7;

    const int endt = cnt[node];
    const float dvd = rsqrtf((float)endt + 1.0f);
    const int end = endt < STRIDE ? endt : STRIDE;
    const int base = node * STRIDE;

    int sv[8];
#pragma unroll
    for (int k = 0; k < 8; ++k) {
        int raw = (int)esrc_pad[base + 8 * k + eidx];
        sv[k] = raw < N_NODES ? raw : (N_NODES - 1);
    }
    float vm[8];
#pragma unroll
    for (int k = 0; k < 8; ++k)
        vm[k] = (8 * k + eidx < end) ? 1.0f : 0.0f;
    half8_t rv[8];
#pragma unroll
    for (int k = 0; k < 8; ++k)
        rv[k] = *(const half8_t*)(g2 + (size_t)sv[k] * 64 + fl * 8);

    float acc[8];
#pragma unroll
    for (int p = 0; p < 8; ++p) acc[p] = 0.0f;
    if (lane < 8) {  // self term g2'[node]
        half8_t s = *(const half8_t*)(g2 + (size_t)node * 64 + fl * 8);
#pragma unroll
        for (int p = 0; p < 8; ++p) acc[p] = (float)s[p];
    }
#pragma unroll
    for (int k = 0; k < 8; ++k)
#pragma unroll
        for (int p = 0; p < 8; ++p) acc[p] += vm[k] * (float)rv[k][p];

    for (int j = 64; j < end; j += 8) {
        int idx = j + eidx;
        int s = (int)esrc_pad[base + ((idx < end) ? idx : (end - 1))];
        float valid = (idx < end) ? 1.0f : 0.0f;
        half8_t r = *(const half8_t*)(g2 + (size_t)s * 64 + fl * 8);
#pragma unroll
        for (int p = 0; p < 8; ++p) acc[p] += valid * (float)r[p];
    }

#pragma unroll
    for (int p = 0; p < 8; ++p) {
        acc[p] += __shfl_xor(acc[p], 8, 64);
        acc[p] += __shfl_xor(acc[p], 16, 64);
        acc[p] += __shfl_xor(acc[p], 32, 64);
    }

    if (lane < 8) {
        float4_t c0 = *(const float4_t*)(b2 + fl * 8);
        float4_t c1 = *(const float4_t*)(b2 + fl * 8 + 4);
        float4_t o0, o1;
        o0[0] = acc[0] * dvd + c0[0]; o0[1] = acc[1] * dvd + c0[1];
        o0[2] = acc[2] * dvd + c0[2]; o0[3] = acc[3] * dvd + c0[3];
        o1[0] = acc[4] * dvd + c1[0]; o1[1] = acc[5] * dvd + c1[1];
        o1[2] = acc[6] * dvd + c1[2]; o1[3] = acc[7] * dvd + c1[3];
        __builtin_nontemporal_store(o0, (float4_t*)(out + (size_t)node * 64 + fl * 8));
        __builtin_nontemporal_store(o1, (float4_t*)(out + (size_t)node * 64 + fl * 8 + 4));
    }
}

extern "C" void kernel_launch(void* const* d_in, const int* in_sizes, int n_in,
                              void* d_out, int out_size, void* d_ws, size_t ws_size,
                              hipStream_t stream) {
    const float* x  = (const float*)d_in[0];
    const int*   ei = (const int*)d_in[1];
    const float* W1 = (const float*)d_in[2];
    const float* b1 = (const float*)d_in[3];
    const float* W2 = (const float*)d_in[4];
    const float* b2 = (const float*)d_in[5];

    const int* src = ei;
    const int* dst = ei + N_EDGES;

    char* w = (char*)d_ws;
    unsigned short* esrc_pad = (unsigned short*)w; w += sizeof(unsigned short) * (size_t)N_NODES * STRIDE;
    _Float16*       GA       = (_Float16*)w;       w += sizeof(_Float16) * (size_t)N_NODES * 64;
    _Float16*       GB       = (_Float16*)w;       w += sizeof(_Float16) * (size_t)N_NODES * 64;
    _Float16*       h1p      = (_Float16*)w;       w += sizeof(_Float16) * (size_t)N_NODES * HID_DIM;
    _Float16*       g2       = (_Float16*)w;       w += sizeof(_Float16) * (size_t)N_NODES * OUT_DIM;
    _Float16*       WT1      = (_Float16*)w;       w += sizeof(_Float16) * 128 * 128;
    _Float16*       WT2      = (_Float16*)w;       w += sizeof(_Float16) * 64 * 128;
    int*            cnt      = (int*)w;            w += sizeof(int) * N_NODES;
    float*          out      = (float*)d_out;

    k_pre<<<PRE_NB, 256, 0, stream>>>(W1, W2, WT1, WT2, cnt);
    k_build<<<SCAT_NB + G1_NB, 256, 0, stream>>>(src, dst, cnt, esrc_pad, WT1, x, GA, GB);
    k_agg1<<<2 * AGG_NB, 256, 0, stream>>>(cnt, esrc_pad, GA, GB, b1, h1p);
    k_g2<<<G1_NB, 256, 0, stream>>>(h1p, WT2, cnt, g2);
    k_agg2<<<AGG_NB, 256, 0, stream>>>(cnt, esrc_pad, g2, b2, out);
}